// Round 2
// baseline (244.008 us; speedup 1.0000x reference)
//
#include <hip/hip_runtime.h>
#include <stdint.h>

// Flash attention fwd, B=16, L=2048, D=128, fp32 in/out.
// R9: FULL FUSION — single kernel, zero workspace. R8 showed attn=50us of
// 137.6us total; prepass+combine+workspace churn = ~88us that no attn-side
// change touches. This kernel eliminates all of it:
//  - grid 256 (16 b x 16 qblk), 512 threads (8 waves = 2/SIMD, 1 block/CU;
//    usable-LDS evidence says ~128KB/CU so one 99KB block is the max anyway).
//  - kv split across wave groups: waves 0-3 do kv[0,32) of each 64-tile,
//    waves 4-7 do kv[32,64). Same per-CU LDS read traffic as 4-wave R32,
//    but 2 waves/SIMD for latency hiding. Partials merged in LDS epilogue.
//  - K staged fp32->bf16 in registers by waves 0-3 (coalesced float4 loads,
//    pk2, swizzled ds_write_b128 — same layout QK^T already reads).
//  - V transposed in-kernel by waves 4-7 with the prepass-verbatim math:
//    reg 8x4 transpose -> vl (stride-72) -> phase-B swizzled V^T in LDS.
//  - O: divide by l, per-wave LDS transpose, coalesced fp32 stores.
// LDS: Kdbuf 32K | Vdbuf 32K | vl 18K | P 16K | ls/inv 1K = 99K.

typedef short bf16x8 __attribute__((ext_vector_type(8)));
typedef float f32x4 __attribute__((ext_vector_type(4)));
typedef unsigned int u32;
typedef unsigned short u16;

#define L_SEQ  2048
#define D_HEAD 128
#define NT     32

#define OFF_K   0        // [2][16384 B]
#define OFF_V   32768    // [2][16384 B]
#define OFF_VL  65536    // 128*72*2 = 18432 B
#define OFF_P   83968    // 8 waves * 2048 B
#define OFF_LS  100352   // 128 * 4 B
#define OFF_INV 100864   // 128 * 4 B
#define LDS_SZ  101376

__device__ __forceinline__ unsigned pk2(float lo, float hi) {
    union { float f; unsigned u; } a, b;
    a.f = lo; b.f = hi;
    return __builtin_amdgcn_perm(b.u + 0x8000u, a.u + 0x8000u, 0x07060302u);
}
__device__ __forceinline__ float ex2(float x) { return __builtin_amdgcn_exp2f(x); }

__global__ __launch_bounds__(512, 2)
void attn_fused(const float* __restrict__ Qg, const float* __restrict__ Kg,
                const float* __restrict__ Vg, float* __restrict__ Og) {
    __shared__ __align__(16) char smem[LDS_SZ];
    const int tid = threadIdx.x;
    const int wv = tid >> 6, lane = tid & 63;
    const int c = lane & 15, qd = lane >> 4, cx = c & 7;
    const int wl = wv & 3, wg = wv >> 2;         // wg: kv-half group
    const int p = blockIdx.x;
    const int b = p >> 4, qblk = p & 15;         // p>>4 = batch: 16 consecutive
                                                 // blocks share K/V (L2 reuse)
    const float* Qp = Qg + (size_t)b * L_SEQ * D_HEAD;
    const float* Kp = Kg + (size_t)b * L_SEQ * D_HEAD;
    const float* Vp = Vg + (size_t)b * L_SEQ * D_HEAD;

    u16* Pl = (u16*)(smem + OFF_P) + wv * 1024;  // 16 rows x 64 u16, s-folded
    const int psw = cx << 1;

    const int vcc = tid & 31, vgk = (tid >> 5) & 7;  // V phase-A mapping
    union { float4 v; float f[4]; } stg[8];          // staging regs (K or V)

    auto stage_load = [&](int tile) {
        if (wg == 0) {   // K: wave wl stages rows [wl*16, wl*16+16)
            const float* base = Kp + (size_t)tile * 64 * 128;
            #pragma unroll
            for (int i = 0; i < 4; ++i) {
                int r = wl * 16 + i * 4 + (lane >> 4);
                int g = lane & 15;
                stg[2*i].v   = *(const float4*)(base + r * 128 + g * 8);
                stg[2*i+1].v = *(const float4*)(base + r * 128 + g * 8 + 4);
            }
        } else {         // V: 256 threads cover the 64x128 tile (prepass map)
            const float* base = Vp + (size_t)(tile * 64 + vgk * 8) * 128 + vcc * 4;
            #pragma unroll
            for (int r = 0; r < 8; ++r)
                stg[r].v = *(const float4*)(base + (size_t)r * 128);
        }
    };
    auto stage_write = [&](int buf) {
        if (wg == 0) {   // K -> bf16, granule swizzle g_stored = g ^ (r&7)
            u16* Kd = (u16*)(smem + OFF_K) + buf * 8192;
            #pragma unroll
            for (int i = 0; i < 4; ++i) {
                int r = wl * 16 + i * 4 + (lane >> 4);
                int g = lane & 15;
                uint4 w;
                w.x = pk2(stg[2*i].f[0],   stg[2*i].f[1]);
                w.y = pk2(stg[2*i].f[2],   stg[2*i].f[3]);
                w.z = pk2(stg[2*i+1].f[0], stg[2*i+1].f[1]);
                w.w = pk2(stg[2*i+1].f[2], stg[2*i+1].f[3]);
                *(uint4*)(Kd + r * 128 + ((g ^ (r & 7)) * 8)) = w;
            }
        } else {         // V reg-transpose -> vl intermediate (stride 72)
            u16* vl = (u16*)(smem + OFF_VL);
            #pragma unroll
            for (int dd = 0; dd < 4; ++dd) {
                uint4 w;
                w.x = pk2(stg[0].f[dd], stg[1].f[dd]);
                w.y = pk2(stg[2].f[dd], stg[3].f[dd]);
                w.z = pk2(stg[4].f[dd], stg[5].f[dd]);
                w.w = pk2(stg[6].f[dd], stg[7].f[dd]);
                *(uint4*)(vl + (vcc * 4 + dd) * 72 + vgk * 8) = w;
            }
        }
    };
    auto phase_b = [&](int buf) {    // vl -> swizzled V^T tile (all 512 thr)
        const u16* vl = (const u16*)(smem + OFF_VL);
        u16* Vd = (u16*)(smem + OFF_V) + buf * 8192;
        #pragma unroll
        for (int i = 0; i < 2; ++i) {
            int flat = tid + 512 * i;
            int d = flat >> 3, gp = flat & 7;
            uint4 w = *(const uint4*)(vl + d * 72 + ((gp ^ (d & 7)) * 8));
            *(uint4*)(Vd + d * 64 + gp * 8) = w;
        }
    };

    // ---- prologue: issue tile-0 loads, build Q fragments, stage tile 0
    stage_load(0);

    const float QS = 1.4426950408889634f / 11.313708498984761f; // log2e/sqrt(128)
    bf16x8 qf[2][4];
    #pragma unroll
    for (int s = 0; s < 2; ++s) {
        const float* qrow = Qp + (size_t)(qblk * 128 + wl * 32 + s * 16 + c) * 128 + qd * 8;
        #pragma unroll
        for (int kt = 0; kt < 4; ++kt) {
            float4 x0 = *(const float4*)(qrow + kt * 32);
            float4 x1 = *(const float4*)(qrow + kt * 32 + 4);
            union { unsigned u[4]; bf16x8 v; } tt;
            tt.u[0] = pk2(x0.x * QS, x0.y * QS);
            tt.u[1] = pk2(x0.z * QS, x0.w * QS);
            tt.u[2] = pk2(x1.x * QS, x1.y * QS);
            tt.u[3] = pk2(x1.z * QS, x1.w * QS);
            qf[s][kt] = tt.v;
        }
    }

    stage_write(0);
    __syncthreads();
    phase_b(0);
    __syncthreads();

    f32x4 acc[2][8];
    #pragma unroll
    for (int s = 0; s < 2; ++s)
        #pragma unroll
        for (int dt = 0; dt < 8; ++dt) acc[s][dt] = (f32x4){0.f, 0.f, 0.f, 0.f};
    float lrun[2] = {0.f, 0.f};

    // ---- main loop: one 64-kv tile per iter; each wave computes its kv-half
    #pragma unroll 2
    for (int it = 0; it < NT; ++it) {
        const int cur = it & 1;
        if (it + 1 < NT) stage_load(it + 1);   // in flight across the compute

        const u16* Kc = (const u16*)(smem + OFF_K) + cur * 8192;
        const u16* Vc = (const u16*)(smem + OFF_V) + cur * 8192;

        // S^T(half) = K(half).Q^T
        f32x4 st[2][2];
        #pragma unroll
        for (int v = 0; v < 2; ++v) {
            st[v][0] = (f32x4){0.f, 0.f, 0.f, 0.f};
            st[v][1] = (f32x4){0.f, 0.f, 0.f, 0.f};
        }
        #pragma unroll
        for (int kt = 0; kt < 4; ++kt) {
            const int g = ((kt * 4 + qd) ^ cx) * 8;
            #pragma unroll
            for (int v = 0; v < 2; ++v) {
                bf16x8 a = *(const bf16x8*)(Kc + (wg * 32 + v * 16 + c) * 128 + g);
                st[v][0] = __builtin_amdgcn_mfma_f32_16x16x32_bf16(a, qf[0][kt], st[v][0], 0, 0, 0);
                st[v][1] = __builtin_amdgcn_mfma_f32_16x16x32_bf16(a, qf[1][kt], st[v][1], 0, 0, 0);
            }
        }

        // sum-only softmax + per-wave swizzled P round-trip (s-folded)
        bf16x8 pf[2];
        #pragma unroll
        for (int s = 0; s < 2; ++s) {
            float lsm = 0.f;
            #pragma unroll
            for (int v = 0; v < 2; ++v) {
                float p0 = ex2(st[v][s].x), p1 = ex2(st[v][s].y);
                float p2 = ex2(st[v][s].z), p3 = ex2(st[v][s].w);
                lsm += (p0 + p1) + (p2 + p3);
                uint2 w; w.x = pk2(p0, p1); w.y = pk2(p2, p3);
                int gsw = (v * 4 + qd) ^ psw;
                *(uint2*)(Pl + c * 64 + gsw * 4) = w;
            }
            lrun[s] += lsm;
            int gsw2 = (qd * 2) ^ psw;
            pf[s] = *(const bf16x8*)(Pl + c * 64 + gsw2 * 4);
            if (s == 0) asm volatile("s_waitcnt lgkmcnt(0)" ::: "memory");
        }

        // O^T(partial) += V^T(half).P^T
        #pragma unroll
        for (int dt = 0; dt < 8; ++dt) {
            bf16x8 a = *(const bf16x8*)(Vc + (dt * 16 + c) * 64 + ((wg * 4 + qd) ^ cx) * 8);
            acc[0][dt] = __builtin_amdgcn_mfma_f32_16x16x32_bf16(a, pf[0], acc[0][dt], 0, 0, 0);
            acc[1][dt] = __builtin_amdgcn_mfma_f32_16x16x32_bf16(a, pf[1], acc[1][dt], 0, 0, 0);
        }

        if (it + 1 < NT) {
            stage_write(1 - cur);   // Kl[nxt] + vl (current-tile bufs untouched)
            __syncthreads();        // vl complete -> phase B may read
            phase_b(1 - cur);
            __syncthreads();        // next tile fully staged
        }
    }

    // ---- epilogue: merge kv-halves, divide by l, transpose, store
    float ls[2];
    #pragma unroll
    for (int s = 0; s < 2; ++s) {
        float l = lrun[s];
        l += __shfl_xor(l, 16);
        l += __shfl_xor(l, 32);
        ls[s] = l;
    }
    __syncthreads();                                // E0: loop LDS dead
    if (wg == 1) {                                  // publish partial acc + l
        f32x4* lin = (f32x4*)(smem + wl * 16384);
        #pragma unroll
        for (int s = 0; s < 2; ++s)
            #pragma unroll
            for (int dt = 0; dt < 8; ++dt)
                lin[(s * 8 + dt) * 64 + lane] = acc[s][dt];
        float* lsl = (float*)(smem + OFF_LS);
        if (qd == 0) {
            lsl[wl * 32 + c]      = ls[0];
            lsl[wl * 32 + 16 + c] = ls[1];
        }
    }
    __syncthreads();                                // E1
    if (wg == 0) {                                  // merge + inverse l
        const f32x4* lin = (const f32x4*)(smem + wl * 16384);
        const float* lsl = (const float*)(smem + OFF_LS);
        float* invl = (float*)(smem + OFF_INV);
        #pragma unroll
        for (int s = 0; s < 2; ++s)
            #pragma unroll
            for (int dt = 0; dt < 8; ++dt)
                acc[s][dt] += lin[(s * 8 + dt) * 64 + lane];
        float l0 = ls[0] + lsl[wl * 32 + c];
        float l1 = ls[1] + lsl[wl * 32 + 16 + c];
        if (qd == 0) {
            invl[wl * 32 + c]      = 1.0f / l0;
            invl[wl * 32 + 16 + c] = 1.0f / l1;
        }
    }
    __syncthreads();                                // E2: lin reads done
    if (wg == 0) {                                  // transposed O into LDS
        float* Ow = (float*)smem + wl * 4224;       // 32 rows x 132 f32
        #pragma unroll
        for (int s = 0; s < 2; ++s)
            #pragma unroll
            for (int dt = 0; dt < 8; ++dt)
                *(f32x4*)(&Ow[(s * 16 + c) * 132 + dt * 16 + qd * 4]) = acc[s][dt];
    }
    __syncthreads();                                // E3
    {                                               // all 8 waves store O
        const float* Ow = (const float*)smem + wl * 4224;
        const float* invl = (const float*)(smem + OFF_INV);
        #pragma unroll
        for (int j = 0; j < 8; ++j) {
            int quad = (wg * 8 + j) * 64 + lane;
            int row = quad >> 5, c4 = quad & 31;
            f32x4 o = *(const f32x4*)(&Ow[row * 132 + c4 * 4]);
            float iv = invl[wl * 32 + row];
            o.x *= iv; o.y *= iv; o.z *= iv; o.w *= iv;
            size_t qr = (size_t)b * L_SEQ + qblk * 128 + wl * 32 + row;
            *(f32x4*)(Og + qr * D_HEAD + c4 * 4) = o;
        }
    }
}

extern "C" void kernel_launch(void* const* d_in, const int* in_sizes, int n_in,
                              void* d_out, int out_size, void* d_ws, size_t ws_size,
                              hipStream_t stream) {
    (void)d_ws; (void)ws_size; (void)in_sizes; (void)n_in; (void)out_size;
    const float* q = (const float*)d_in[0];
    const float* k = (const float*)d_in[1];
    const float* v = (const float*)d_in[2];
    float* out = (float*)d_out;
    attn_fused<<<dim3(256), dim3(512), 0, stream>>>(q, k, v, out);
}

// Round 3
// 209.597 us; speedup vs baseline: 1.1642x; 1.1642x over previous
//
#include <hip/hip_runtime.h>
#include <stdint.h>

// Flash attention fwd, B=16, L=2048, D=128, fp32 in/out.
// R10: back to 3-kernel (R9 fusion post-mortem: conversion must be shared).
// attn restructured for the LDS-issue bound (R7/R8: 7.5 LDS-cyc per MFMA):
//  - Wq=64 q-rows per wave (s=0..3): each K/V b128 fragment read feeds 4
//    MFMAs instead of 2 -> 4.5 LDS-cyc/MFMA, ~15us/CU LDS floor (was 26).
//  - in-block kv-split: waves 0-3 take kv[0,32), waves 4-7 kv[32,64) of each
//    tile; partial acc+l merged through LDS in the epilogue.
//  - grid 256 = 16b x 8qblk(256q) x 2 kvh; 512 thr; 1 block/CU, 2 waves/SIMD.
//  - K/V double-buffered (16KB each x2), ONE barrier per tile.
//  - P: per-wave 64 rows x 32kv, row stride 40 u16 (80 B) -> banks spread by
//    row, no swizzle; writes 2-way (free), reads standard b128 wrap.
// prepass unchanged. combine sums 2 kv-halves, 128 q-rows per wg.
// WS: kb 8.4M | vt 8.4M | part 256x64KB=16.8M | lsum 256KB = 33.8 MB.

typedef short bf16x8 __attribute__((ext_vector_type(8)));
typedef float f32x4 __attribute__((ext_vector_type(4)));
typedef unsigned int u32;
typedef unsigned short u16;

#define L_SEQ  2048
#define D_HEAD 128
#define TSZ    8388608u                          // bytes per bf16 tensor
#define W_PART (2u * TSZ)                        // 256 x 64 KB partials
#define W_LSUM (W_PART + 256u * 65536u)
#define WS_NEED (W_LSUM + 256u * 256u * 4u)      // 33,816,576 B

__device__ __forceinline__ unsigned pk2(float lo, float hi) {
    union { float f; unsigned u; } a, b;
    a.f = lo; b.f = hi;
    return __builtin_amdgcn_perm(b.u + 0x8000u, a.u + 0x8000u, 0x07060302u);
}
__device__ __forceinline__ float ex2(float x) { return __builtin_amdgcn_exp2f(x); }
__device__ __forceinline__ float bflo(unsigned w) {
    union { unsigned u; float f; } v; v.u = w << 16; return v.f;
}
__device__ __forceinline__ float bfhi(unsigned w) {
    union { unsigned u; float f; } v; v.u = w & 0xffff0000u; return v.f;
}
__device__ __forceinline__ void gl_lds16(const u16* g, u16* l) {
    __builtin_amdgcn_global_load_lds(
        (const __attribute__((address_space(1))) u32*)g,
        (__attribute__((address_space(3))) u32*)l, 16, 0, 0);
}

// ---------------- pre-pass (unchanged, proven) -----------------------------
// wg 0..511:  K -> bf16 rows, granule swizzle gp_stored = gp_logical^(row&7)
// wg 512..1023: V -> V^T bf16 tiles [tile][d=128][8 gp swz][8 kv], vectorized
__global__ __launch_bounds__(256, 4)
void prepass(const float* __restrict__ K, const float* __restrict__ V,
             u16* __restrict__ kb, u16* __restrict__ vt) {
    const int id = blockIdx.x, t = threadIdx.x;
    if (id < 512) {
        const float* src = K + (size_t)id * 64 * 128;
        u16*        dst = kb + (size_t)id * 64 * 128;
        const int r = t >> 2;
        #pragma unroll
        for (int i = 0; i < 4; ++i) {
            int gp = (t & 3) * 4 + i;
            int gs = gp ^ (r & 7);
            const float* s = src + r * 128 + gs * 8;
            float4 x0 = *(const float4*)s, x1 = *(const float4*)(s + 4);
            uint4 w;
            w.x = pk2(x0.x, x0.y); w.y = pk2(x0.z, x0.w);
            w.z = pk2(x1.x, x1.y); w.w = pk2(x1.z, x1.w);
            *(uint4*)(dst + r * 128 + gp * 8) = w;
        }
    } else {
        __shared__ __align__(16) u16 vl[128 * 72];
        const int bid = id - 512;
        const float* src = V + (size_t)bid * 64 * 128;
        const int vcc = t & 31, vgk = t >> 5;
        union { float4 v; float f[4]; } vr[8];
        const float* vp = src + (size_t)(vgk * 8) * 128 + vcc * 4;
        #pragma unroll
        for (int r = 0; r < 8; ++r) vr[r].v = *(const float4*)(vp + (size_t)r * 128);
        #pragma unroll
        for (int dd = 0; dd < 4; ++dd) {
            uint4 w;
            w.x = pk2(vr[0].f[dd], vr[1].f[dd]);
            w.y = pk2(vr[2].f[dd], vr[3].f[dd]);
            w.z = pk2(vr[4].f[dd], vr[5].f[dd]);
            w.w = pk2(vr[6].f[dd], vr[7].f[dd]);
            *(uint4*)(&vl[(vcc * 4 + dd) * 72 + vgk * 8]) = w;
        }
        __syncthreads();
        u16* dst = vt + (size_t)bid * 8192;
        #pragma unroll
        for (int i = 0; i < 4; ++i) {
            int flat = t + 256 * i;
            int d = flat >> 3, gp = flat & 7;
            uint4 w = *(const uint4*)(&vl[d * 72 + ((gp ^ (d & 7)) * 8)]);
            *(uint4*)(dst + (size_t)flat * 8) = w;
        }
    }
}

// ---------------- main kernel ---------------------------------------------
// LDS: Kdbuf [2][16KB] @0, Vdbuf [2][16KB] @32768, P @65536 (8wv x 5120B)
__global__ __launch_bounds__(512, 2)
void attn5(const float* __restrict__ Qg, const u16* __restrict__ kb,
           const u16* __restrict__ vt, u16* __restrict__ part,
           float* __restrict__ lsum) {
    __shared__ __align__(16) char smem[106496];
    const int tid = threadIdx.x;
    const int wv = tid >> 6, lane = tid & 63;
    const int c = lane & 15, qd = lane >> 4, cx = c & 7;
    const int wl = wv & 3, wg2 = wv >> 2;        // wl: q 64-block, wg2: kv half
    const int bid = blockIdx.x;
    const int kvh = bid >> 7, pidx = bid & 127;  // kvh in {0,1}
    const int b = pidx & 15, qblk = pidx >> 4;   // qblk 0..7 (256 q each)
    const int nt = 16;                           // 64-kv tiles per wg

    const float* Qp = Qg + (size_t)b * L_SEQ * D_HEAD;
    const u16*   Kp = kb + (size_t)b * L_SEQ * D_HEAD + (size_t)kvh * 16 * 8192;
    const u16*   Vp = vt + (size_t)b * 32 * 8192 + (size_t)kvh * 16 * 8192;
    u16* Pl = (u16*)(smem + 65536) + wv * 2560;  // 64 rows x 40 u16 (8 gran+pad)

    const int so = tid * 8;                      // DMA offset, u16 units

    auto stage = [&](int t, int buf) {
        u16* Kd = (u16*)smem + buf * 8192;
        u16* Vd = (u16*)(smem + 32768) + buf * 8192;
        const u16* kg = Kp + (size_t)t * 8192;
        const u16* vg = Vp + (size_t)t * 8192;
        gl_lds16(kg + so, Kd + so);
        gl_lds16(kg + so + 4096, Kd + so + 4096);
        gl_lds16(vg + so, Vd + so);
        gl_lds16(vg + so + 4096, Vd + so + 4096);
    };

    stage(0, 0);

    const float QS = 1.4426950408889634f / 11.313708498984761f; // log2e/sqrt(128)
    bf16x8 qf[4][4];
    #pragma unroll
    for (int s = 0; s < 4; ++s) {
        const float* qrow = Qp + (size_t)(qblk * 256 + wl * 64 + s * 16 + c) * 128 + qd * 8;
        #pragma unroll
        for (int kt = 0; kt < 4; ++kt) {
            float4 x0 = *(const float4*)(qrow + kt * 32);
            float4 x1 = *(const float4*)(qrow + kt * 32 + 4);
            union { unsigned u[4]; bf16x8 v; } tt;
            tt.u[0] = pk2(x0.x * QS, x0.y * QS);
            tt.u[1] = pk2(x0.z * QS, x0.w * QS);
            tt.u[2] = pk2(x1.x * QS, x1.y * QS);
            tt.u[3] = pk2(x1.z * QS, x1.w * QS);
            qf[s][kt] = tt.v;
        }
    }

    f32x4 acc[4][8];
    #pragma unroll
    for (int s = 0; s < 4; ++s)
        #pragma unroll
        for (int dt = 0; dt < 8; ++dt) acc[s][dt] = (f32x4){0.f, 0.f, 0.f, 0.f};
    float lrun[4] = {0.f, 0.f, 0.f, 0.f};

    __syncthreads();   // tile 0 staged (implicit vmcnt drain)

    #pragma unroll 2
    for (int it = 0; it < nt; ++it) {
        const int cur = it & 1;
        if (it + 1 < nt) stage(it + 1, cur ^ 1);   // full tile of hiding

        const u16* Kc = (const u16*)smem + cur * 8192;
        const u16* Vc = (const u16*)(smem + 32768) + cur * 8192;

        // ---- S^T(32kv x 64q) = K(half).Q^T, exp, P-write (per 16-kv chunk)
        #pragma unroll
        for (int vl2 = 0; vl2 < 2; ++vl2) {
            f32x4 st[4];
            #pragma unroll
            for (int s = 0; s < 4; ++s) st[s] = (f32x4){0.f, 0.f, 0.f, 0.f};
            #pragma unroll
            for (int kt = 0; kt < 4; ++kt) {
                bf16x8 a = *(const bf16x8*)(Kc + (wg2 * 32 + vl2 * 16 + c) * 128
                                               + ((kt * 4 + qd) ^ cx) * 8);
                #pragma unroll
                for (int s = 0; s < 4; ++s)
                    st[s] = __builtin_amdgcn_mfma_f32_16x16x32_bf16(a, qf[s][kt], st[s], 0, 0, 0);
            }
            #pragma unroll
            for (int s = 0; s < 4; ++s) {
                float p0 = ex2(st[s].x), p1 = ex2(st[s].y);
                float p2 = ex2(st[s].z), p3 = ex2(st[s].w);
                lrun[s] += (p0 + p1) + (p2 + p3);
                uint2 w; w.x = pk2(p0, p1); w.y = pk2(p2, p3);
                *(uint2*)(Pl + (s * 16 + c) * 40 + (vl2 * 4 + qd) * 4) = w;
            }
        }
        // wave-internal cross-lane WAR/RAW guard for the P round-trip
        asm volatile("s_waitcnt lgkmcnt(0)" ::: "memory");
        bf16x8 pf[4];
        #pragma unroll
        for (int s = 0; s < 4; ++s)
            pf[s] = *(const bf16x8*)(Pl + (s * 16 + c) * 40 + qd * 8);

        // ---- O^T(partial) += V^T(half).P^T
        #pragma unroll
        for (int dt = 0; dt < 8; ++dt) {
            bf16x8 av = *(const bf16x8*)(Vc + (dt * 16 + c) * 64
                                            + ((wg2 * 4 + qd) ^ cx) * 8);
            #pragma unroll
            for (int s = 0; s < 4; ++s)
                acc[s][dt] = __builtin_amdgcn_mfma_f32_16x16x32_bf16(av, pf[s], acc[s][dt], 0, 0, 0);
        }

        if (it + 1 < nt) __syncthreads();   // next-tile DMA drained; bufs free
    }

    // ---- epilogue: qd-reduce l, merge kv-halves via LDS, store partials
    float ls[4];
    #pragma unroll
    for (int s = 0; s < 4; ++s) {
        float l = lrun[s];
        l += __shfl_xor(l, 16);
        l += __shfl_xor(l, 32);
        ls[s] = l;
    }
    float* lsh = (float*)(smem + 65536);
    __syncthreads();                               // E0: loop LDS dead
    if (wg2 == 1) {
        if (qd == 0) {
            #pragma unroll
            for (int s = 0; s < 4; ++s) lsh[wl * 64 + s * 16 + c] = ls[s];
        }
        #pragma unroll
        for (int s2 = 0; s2 < 2; ++s2)
            #pragma unroll
            for (int dt = 0; dt < 8; ++dt)
                *(f32x4*)(smem + ((((s2 * 4 + wl) * 8 + dt) << 10) + lane * 16)) = acc[s2][dt];
    }
    __syncthreads();                               // E1
    float lf[4] = {0.f, 0.f, 0.f, 0.f};
    if (wg2 == 0) {
        #pragma unroll
        for (int s = 0; s < 4; ++s) lf[s] = ls[s] + lsh[wl * 64 + s * 16 + c];
        #pragma unroll
        for (int s2 = 0; s2 < 2; ++s2)
            #pragma unroll
            for (int dt = 0; dt < 8; ++dt)
                acc[s2][dt] += *(const f32x4*)(smem + ((((s2 * 4 + wl) * 8 + dt) << 10) + lane * 16));
    }
    __syncthreads();                               // E2: s01 reads done
    if (wg2 == 1) {
        #pragma unroll
        for (int s2 = 0; s2 < 2; ++s2)
            #pragma unroll
            for (int dt = 0; dt < 8; ++dt)
                *(f32x4*)(smem + ((((s2 * 4 + wl) * 8 + dt) << 10) + lane * 16)) = acc[2 + s2][dt];
    }
    __syncthreads();                               // E3
    if (wg2 == 0) {
        #pragma unroll
        for (int s2 = 0; s2 < 2; ++s2)
            #pragma unroll
            for (int dt = 0; dt < 8; ++dt)
                acc[2 + s2][dt] += *(const f32x4*)(smem + ((((s2 * 4 + wl) * 8 + dt) << 10) + lane * 16));
        u16* pb = part + (size_t)bid * 32768 + wl * 8192;
        #pragma unroll
        for (int s = 0; s < 4; ++s)
            #pragma unroll
            for (int dt = 0; dt < 8; ++dt) {
                f32x4 o = acc[s][dt];
                uint2 w; w.x = pk2(o.x, o.y); w.y = pk2(o.z, o.w);
                *(uint2*)(pb + (((s * 8 + dt) * 64 + lane) << 2)) = w;
            }
        if (qd == 0) {
            #pragma unroll
            for (int s = 0; s < 4; ++s)
                lsum[bid * 256 + wl * 64 + s * 16 + c] = lf[s];
        }
    }
}

// ---------------- combine: O = (O0+O1)/(l0+l1), transpose, store -----------
__global__ __launch_bounds__(256, 2)
void combine5(const u16* __restrict__ part, const float* __restrict__ lsum,
              float* __restrict__ Og) {
    __shared__ float inv[128];
    __shared__ __align__(16) float Ol[64 * 132];
    const int t = threadIdx.x, p = blockIdx.x;
    const int pidx = p >> 1, half = p & 1;
    const int b = pidx & 15, qblk = pidx >> 4;
    if (t < 128) {
        float l0 = lsum[(size_t)pidx * 256 + half * 128 + t];
        float l1 = lsum[(size_t)(128 + pidx) * 256 + half * 128 + t];
        inv[t] = 1.0f / (l0 + l1);
    }
    __syncthreads();
    #pragma unroll
    for (int wlh = 0; wlh < 2; ++wlh) {
        const int wl = half * 2 + wlh;
        const uint2* S0 = (const uint2*)(part + (size_t)pidx * 32768 + wl * 8192);
        const uint2* S1 = (const uint2*)(part + (size_t)(128 + pidx) * 32768 + wl * 8192);
        #pragma unroll
        for (int i = 0; i < 8; ++i) {
            int slot = i * 256 + t;
            int lc = slot >> 6, lane = slot & 63;
            int s = lc >> 3, dt = lc & 7;
            int qd = lane >> 4, cc = lane & 15;
            int row = s * 16 + cc;
            int d0 = dt * 16 + qd * 4;
            uint2 w0 = S0[slot], w1 = S1[slot];
            float iv = inv[wlh * 64 + row];
            float4 o;
            o.x = (bflo(w0.x) + bflo(w1.x)) * iv;
            o.y = (bfhi(w0.x) + bfhi(w1.x)) * iv;
            o.z = (bflo(w0.y) + bflo(w1.y)) * iv;
            o.w = (bfhi(w0.y) + bfhi(w1.y)) * iv;
            *(float4*)(&Ol[row * 132 + d0]) = o;
        }
        __syncthreads();
        #pragma unroll
        for (int i = 0; i < 8; ++i) {
            int slot = i * 256 + t;
            int row = slot >> 5, c4 = slot & 31;
            float4 val = *(const float4*)(&Ol[row * 132 + c4 * 4]);
            size_t q = (size_t)b * L_SEQ + qblk * 256 + half * 128 + wlh * 64 + row;
            *(float4*)(Og + q * D_HEAD + c4 * 4) = val;
        }
        __syncthreads();
    }
}

extern "C" void kernel_launch(void* const* d_in, const int* in_sizes, int n_in,
                              void* d_out, int out_size, void* d_ws, size_t ws_size,
                              hipStream_t stream) {
    const float* q = (const float*)d_in[0];
    const float* k = (const float*)d_in[1];
    const float* v = (const float*)d_in[2];
    float* out = (float*)d_out;
    u16* kb = (u16*)d_ws;
    u16* vt = (u16*)((char*)d_ws + TSZ);
    u16* part = (u16*)((char*)d_ws + W_PART);
    float* ls = (float*)((char*)d_ws + W_LSUM);
    prepass<<<dim3(1024), dim3(256), 0, stream>>>(k, v, kb, vt);
    attn5<<<dim3(256), dim3(512), 0, stream>>>(q, kb, vt, part, ls);
    combine5<<<dim3(256), dim3(256), 0, stream>>>(part, ls, out);
}

// Round 4
// 139.686 us; speedup vs baseline: 1.7468x; 1.5005x over previous
//
#include <hip/hip_runtime.h>
#include <stdint.h>

// Flash attention fwd, B=16, L=2048, D=128, fp32 in/out.
// R11: R7's proven attn3 (50us, 2 barriers/tile, single-buffered K/V,
// kv-split x3) with ONE change: the P buffer is s-folded (R8's proven
// pattern, 2 KB/wave) so LDS drops 48 KB -> 40 KB. Usable-LDS evidence
// (R7: 48K->2 blk, R8: 72K->1.4 blk) says ~128 KB/CU usable => 40 KB
// fits 3 blocks/CU. Grid 768 = exactly 3 wgs/CU -> 12 waves/CU (36%),
// +50% latency-hiding at the measured-best structure.
// prepass/combine3/workspace identical to R7.

typedef short bf16x8 __attribute__((ext_vector_type(8)));
typedef float f32x4 __attribute__((ext_vector_type(4)));
typedef unsigned int u32;
typedef unsigned short u16;

#define L_SEQ  2048
#define D_HEAD 128
#define TSZ    8388608u                          // bytes per bf16 tensor
#define W_PART (2u * TSZ)                        // 768 x 32 KB partials
#define W_LSUM (W_PART + 768u * 32768u)
#define WS_NEED (W_LSUM + 768u * 128u * 4u)      // 42,336,256 B

__device__ __forceinline__ unsigned pk2(float lo, float hi) {
    union { float f; unsigned u; } a, b;
    a.f = lo; b.f = hi;
    return __builtin_amdgcn_perm(b.u + 0x8000u, a.u + 0x8000u, 0x07060302u);
}
__device__ __forceinline__ float ex2(float x) { return __builtin_amdgcn_exp2f(x); }
__device__ __forceinline__ float bflo(unsigned w) {
    union { unsigned u; float f; } v; v.u = w << 16; return v.f;
}
__device__ __forceinline__ float bfhi(unsigned w) {
    union { unsigned u; float f; } v; v.u = w & 0xffff0000u; return v.f;
}
__device__ __forceinline__ void gl_lds16(const u16* g, u16* l) {
    __builtin_amdgcn_global_load_lds(
        (const __attribute__((address_space(1))) u32*)g,
        (__attribute__((address_space(3))) u32*)l, 16, 0, 0);
}

// ---------------- pre-pass (unchanged, proven) -----------------------------
// wg 0..511:  K -> bf16 rows, granule swizzle gp_stored = gp_logical^(row&7)
// wg 512..1023: V -> V^T bf16 tiles [tile][d=128][8 gp swz][8 kv], vectorized
__global__ __launch_bounds__(256, 4)
void prepass(const float* __restrict__ K, const float* __restrict__ V,
             u16* __restrict__ kb, u16* __restrict__ vt) {
    const int id = blockIdx.x, t = threadIdx.x;
    if (id < 512) {
        const float* src = K + (size_t)id * 64 * 128;
        u16*        dst = kb + (size_t)id * 64 * 128;
        const int r = t >> 2;
        #pragma unroll
        for (int i = 0; i < 4; ++i) {
            int gp = (t & 3) * 4 + i;
            int gs = gp ^ (r & 7);
            const float* s = src + r * 128 + gs * 8;
            float4 x0 = *(const float4*)s, x1 = *(const float4*)(s + 4);
            uint4 w;
            w.x = pk2(x0.x, x0.y); w.y = pk2(x0.z, x0.w);
            w.z = pk2(x1.x, x1.y); w.w = pk2(x1.z, x1.w);
            *(uint4*)(dst + r * 128 + gp * 8) = w;
        }
    } else {
        // V^T: register 8x4 transpose -> LDS rows (b128) -> swizzled stores
        __shared__ __align__(16) u16 vl[128 * 72];
        const int bid = id - 512;
        const float* src = V + (size_t)bid * 64 * 128;
        const int vcc = t & 31, vgk = t >> 5;
        union { float4 v; float f[4]; } vr[8];
        const float* vp = src + (size_t)(vgk * 8) * 128 + vcc * 4;
        #pragma unroll
        for (int r = 0; r < 8; ++r) vr[r].v = *(const float4*)(vp + (size_t)r * 128);
        #pragma unroll
        for (int dd = 0; dd < 4; ++dd) {
            uint4 w;
            w.x = pk2(vr[0].f[dd], vr[1].f[dd]);
            w.y = pk2(vr[2].f[dd], vr[3].f[dd]);
            w.z = pk2(vr[4].f[dd], vr[5].f[dd]);
            w.w = pk2(vr[6].f[dd], vr[7].f[dd]);
            *(uint4*)(&vl[(vcc * 4 + dd) * 72 + vgk * 8]) = w;
        }
        __syncthreads();
        u16* dst = vt + (size_t)bid * 8192;
        #pragma unroll
        for (int i = 0; i < 4; ++i) {
            int flat = t + 256 * i;
            int d = flat >> 3, gp = flat & 7;
            uint4 w = *(const uint4*)(&vl[d * 72 + ((gp ^ (d & 7)) * 8)]);
            *(uint4*)(dst + (size_t)flat * 8) = w;
        }
    }
}

// ---------------- main kernel: kv third per wg -----------------------------
// LDS: Kbuf 0..16K, Vbuf 16K..32K, P 32K..40K (4 waves x 16 x 64 u16 folded)
__global__ __launch_bounds__(256, 3)
void attn3(const float* __restrict__ Qg, const u16* __restrict__ kb,
           const u16* __restrict__ vt, u16* __restrict__ part,
           float* __restrict__ lsum) {
    __shared__ __align__(16) char smem[40960];
    const int tid = threadIdx.x;
    const int wv = tid >> 6, lane = tid & 63;
    const int c = lane & 15, qd = lane >> 4, cx = c & 7;
    const int bid = blockIdx.x;
    const int p = bid & 255, kvh = bid >> 8;       // kvh in {0,1,2}
    const int b = p & 15, qblk = p >> 4;
    const int t0 = kvh * 11;                       // first 64-tile
    const int nt = (kvh < 2) ? 11 : 10;            // tiles this wg

    const float* Qp = Qg + (size_t)b * L_SEQ * D_HEAD;
    const u16*   Kp = kb + (size_t)b * L_SEQ * D_HEAD + (size_t)t0 * 8192;
    const u16*   Vp = vt + (size_t)b * 32 * 8192 + (size_t)t0 * 8192;
    u16* Kl = (u16*)smem;
    u16* Vl = (u16*)(smem + 16384);
    u16* Pl = (u16*)(smem + 32768) + wv * 1024;    // 16 rows x 64 u16, s-folded

    const int so = wv * 2048 + lane * 8;           // DMA offset, u16 units
    const int psw = (c & 7) << 1;                  // P granule swizzle constant

    #pragma unroll
    for (int i = 0; i < 4; ++i) {
        gl_lds16(Kp + so + i * 512, Kl + so + i * 512);
        gl_lds16(Vp + so + i * 512, Vl + so + i * 512);
    }

    const float QS = 1.4426950408889634f / 11.313708498984761f; // log2e/sqrt(128)
    bf16x8 qf[2][4];
    #pragma unroll
    for (int s = 0; s < 2; ++s) {
        const float* qrow = Qp + (size_t)(qblk * 128 + wv * 32 + s * 16 + c) * 128 + qd * 8;
        #pragma unroll
        for (int kt = 0; kt < 4; ++kt) {
            float4 x0 = *(const float4*)(qrow + kt * 32);
            float4 x1 = *(const float4*)(qrow + kt * 32 + 4);
            union { unsigned u[4]; bf16x8 v; } tt;
            tt.u[0] = pk2(x0.x * QS, x0.y * QS);
            tt.u[1] = pk2(x0.z * QS, x0.w * QS);
            tt.u[2] = pk2(x1.x * QS, x1.y * QS);
            tt.u[3] = pk2(x1.z * QS, x1.w * QS);
            qf[s][kt] = tt.v;
        }
    }

    f32x4 acc[2][8];
    #pragma unroll
    for (int s = 0; s < 2; ++s)
        #pragma unroll
        for (int dt = 0; dt < 8; ++dt) acc[s][dt] = (f32x4){0.f, 0.f, 0.f, 0.f};
    float lrun[2] = {0.f, 0.f};

    __syncthreads();   // tile 0 arrived

    for (int it = 0; it < nt; ++it) {
        // ---- S^T = K.Q^T
        f32x4 st[4][2];
        #pragma unroll
        for (int v = 0; v < 4; ++v) {
            st[v][0] = (f32x4){0.f, 0.f, 0.f, 0.f};
            st[v][1] = (f32x4){0.f, 0.f, 0.f, 0.f};
        }
        #pragma unroll
        for (int kt = 0; kt < 4; ++kt) {
            const int g = ((kt * 4 + qd) ^ cx) * 8;
            #pragma unroll
            for (int v = 0; v < 4; ++v) {
                bf16x8 a = *(const bf16x8*)(Kl + (v * 16 + c) * 128 + g);
                st[v][0] = __builtin_amdgcn_mfma_f32_16x16x32_bf16(a, qf[0][kt], st[v][0], 0, 0, 0);
                st[v][1] = __builtin_amdgcn_mfma_f32_16x16x32_bf16(a, qf[1][kt], st[v][1], 0, 0, 0);
            }
        }
        __syncthreads();   // barrier 1: V(it) DMA drained; K-reads done

        if (it + 1 < nt) {
            const u16* kg = Kp + (size_t)(it + 1) * 8192 + so;
            #pragma unroll
            for (int i = 0; i < 4; ++i) gl_lds16(kg + i * 512, Kl + so + i * 512);
        }

        // ---- sum-only softmax + per-wave swizzled P round-trip (s-folded)
        bf16x8 pf[2][2];
        #pragma unroll
        for (int s = 0; s < 2; ++s) {
            float lsm = 0.f;
            #pragma unroll
            for (int v = 0; v < 4; ++v) {
                float p0 = ex2(st[v][s].x), p1 = ex2(st[v][s].y);
                float p2 = ex2(st[v][s].z), p3 = ex2(st[v][s].w);
                lsm += (p0 + p1) + (p2 + p3);
                uint2 w; w.x = pk2(p0, p1); w.y = pk2(p2, p3);
                int gsw = (v * 4 + qd) ^ psw;           // granule swizzle
                *(uint2*)(Pl + c * 64 + gsw * 4) = w;
            }
            lrun[s] += lsm;
            #pragma unroll
            for (int h = 0; h < 2; ++h) {
                int gsw = (h * 8 + qd * 2) ^ psw;       // even: b128 contiguous
                pf[h][s] = *(const bf16x8*)(Pl + c * 64 + gsw * 4);
            }
            if (s == 0) asm volatile("s_waitcnt lgkmcnt(0)" ::: "memory");
        }

        // ---- O^T += V^T.P^T
        #pragma unroll
        for (int dt = 0; dt < 8; ++dt) {
            #pragma unroll
            for (int h = 0; h < 2; ++h) {
                bf16x8 a = *(const bf16x8*)(Vl + (dt * 16 + c) * 64 + ((h * 4 + qd) ^ cx) * 8);
                acc[0][dt] = __builtin_amdgcn_mfma_f32_16x16x32_bf16(a, pf[h][0], acc[0][dt], 0, 0, 0);
                acc[1][dt] = __builtin_amdgcn_mfma_f32_16x16x32_bf16(a, pf[h][1], acc[1][dt], 0, 0, 0);
            }
        }
        __syncthreads();   // barrier 2: K(it+1) DMA drained; V-reads done

        if (it + 1 < nt) {
            const u16* vg = Vp + (size_t)(it + 1) * 8192 + so;
            #pragma unroll
            for (int i = 0; i < 4; ++i) gl_lds16(vg + i * 512, Vl + so + i * 512);
        }
    }

    // ---- epilogue: reduce l, write bf16 O^T-partial + l
    float ls[2];
    #pragma unroll
    for (int s = 0; s < 2; ++s) {
        float l = lrun[s];
        l += __shfl_xor(l, 16);
        l += __shfl_xor(l, 32);
        ls[s] = l;
    }
    u16* pb = part + (size_t)bid * 16384;   // 32 KB per wg
    #pragma unroll
    for (int s = 0; s < 2; ++s)
        #pragma unroll
        for (int dt = 0; dt < 8; ++dt) {
            f32x4 o = acc[s][dt];
            uint2 w; w.x = pk2(o.x, o.y); w.y = pk2(o.z, o.w);
            *(uint2*)(pb + ((((wv * 2 + s) * 8 + dt) * 64 + lane) << 2)) = w;
        }
    if (qd == 0) {
        lsum[kvh * 32768 + p * 128 + wv * 32 + c]      = ls[0];
        lsum[kvh * 32768 + p * 128 + wv * 32 + 16 + c] = ls[1];
    }
}

// ---------------- combine3: O = (O0+O1+O2)/(l0+l1+l2), transpose, store ----
__global__ __launch_bounds__(256, 2)
void combine3(const u16* __restrict__ part, const float* __restrict__ lsum,
              float* __restrict__ Og) {
    __shared__ float inv[128];
    __shared__ __align__(16) float Ol[64 * 132];
    const int t = threadIdx.x, p = blockIdx.x;
    const int b = p & 15, qblk = p >> 4;
    if (t < 128) {
        float l0 = lsum[p * 128 + t];
        float l1 = lsum[32768 + p * 128 + t];
        float l2 = lsum[65536 + p * 128 + t];
        inv[t] = 1.0f / (l0 + l1 + l2);
    }
    const uint2* P0 = (const uint2*)(part + (size_t)p * 16384);
    const uint2* P1 = (const uint2*)(part + (size_t)(256 + p) * 16384);
    const uint2* P2 = (const uint2*)(part + (size_t)(512 + p) * 16384);
    __syncthreads();
    #pragma unroll
    for (int h = 0; h < 2; ++h) {
        #pragma unroll
        for (int i = 0; i < 8; ++i) {
            int slot = i * 256 + t;
            int lc = slot >> 6, lane = slot & 63;
            int gc = h * 32 + lc;
            int s = (lc >> 3) & 1, dt = lc & 7;
            int qd = lane >> 4, c = lane & 15;
            int row = (lc >> 4) * 32 + s * 16 + c;
            int d0 = dt * 16 + qd * 4;
            size_t idx = (size_t)gc * 64 + lane;
            uint2 w0 = P0[idx], w1 = P1[idx], w2 = P2[idx];
            float iv = inv[h * 64 + row];
            float4 o;
            o.x = (bflo(w0.x) + bflo(w1.x) + bflo(w2.x)) * iv;
            o.y = (bfhi(w0.x) + bfhi(w1.x) + bfhi(w2.x)) * iv;
            o.z = (bflo(w0.y) + bflo(w1.y) + bflo(w2.y)) * iv;
            o.w = (bfhi(w0.y) + bfhi(w1.y) + bfhi(w2.y)) * iv;
            *(float4*)(&Ol[row * 132 + d0]) = o;
        }
        __syncthreads();
        #pragma unroll
        for (int i = 0; i < 8; ++i) {
            int slot = i * 256 + t;
            int row = slot >> 5, c4 = slot & 31;
            float4 val = *(const float4*)(&Ol[row * 132 + c4 * 4]);
            size_t q = (size_t)b * L_SEQ + qblk * 128 + h * 64 + row;
            *(float4*)(Og + q * D_HEAD + c4 * 4) = val;
        }
        __syncthreads();
    }
}

extern "C" void kernel_launch(void* const* d_in, const int* in_sizes, int n_in,
                              void* d_out, int out_size, void* d_ws, size_t ws_size,
                              hipStream_t stream) {
    const float* q = (const float*)d_in[0];
    const float* k = (const float*)d_in[1];
    const float* v = (const float*)d_in[2];
    float* out = (float*)d_out;
    u16* kb = (u16*)d_ws;
    u16* vt = (u16*)((char*)d_ws + TSZ);
    u16* part = (u16*)((char*)d_ws + W_PART);
    float* ls = (float*)((char*)d_ws + W_LSUM);
    prepass<<<dim3(1024), dim3(256), 0, stream>>>(k, v, kb, vt);
    attn3<<<dim3(768), dim3(256), 0, stream>>>(q, kb, vt, part, ls);
    combine3<<<dim3(256), dim3(256), 0, stream>>>(part, ls, out);
}